// Round 12
// baseline (2130.795 us; speedup 1.0000x reference)
//
#include <hip/hip_runtime.h>

// MultiLayerLSTM: B=256, T=1024, V=27, E=64, H=128 (4H=512)
// Round 12: halve BOTH bound pipes in the recurrences.
//   r11 arithmetic: DS ~800 cyc/step (64 ds_read_b128/CU) + VALU ~850
//   (128 scalar FMA + overhead, 2 waves/SIMD) ≈ observed 1690 cyc/step.
//   - thread=(row-pair, k-eighth): 16 h/thread -> 4 b128 (DS halves)
//   - v_pk_fma_f32 inline asm: 64 packed FMA (FMA issue halves)
//   - 8-lane all-reduce (sum8) + 7-cndmask combo select; activation on all
//     8 lanes (combo q = row q>>2, gate q&3); quad-DPP cell update lanes 0,4
//   - table0 addend from global/L2 with 1-step prefetch (tabS LDS gone)
// Phases: P0 table, P1 l0, P2 GEMM xg1=h0@wx1+b1, P3 l1, P4 proj_y.

#define B_  256
#define T_  1024
#define V_  27
#define E_  64
#define H_  128
#define G4  512     // 4*H
#define TPITCH 528  // 4*132 padded table pitch per vocab entry

typedef float v2f __attribute__((ext_vector_type(2)));
typedef float v4f __attribute__((ext_vector_type(4)));

__device__ __forceinline__ v2f mkv2(float a, float b) { v2f r; r.x = a; r.y = b; return r; }

template <int CTRL>
__device__ __forceinline__ float dppmov(float v) {
    return __int_as_float(__builtin_amdgcn_update_dpp(
               0, __float_as_int(v), CTRL, 0xF, 0xF, true));
}
// all-reduce sum over aligned 8-lane group (xor1, xor2, half-row mirror)
__device__ __forceinline__ float sum8(float v) {
    v += dppmov<0xB1>(v);
    v += dppmov<0x4E>(v);
    v += dppmov<0x141>(v);
    return v;
}
__device__ __forceinline__ float tanh_fast(float y) {
    const float t = __expf(2.f * y);             // inf-safe: tanh(+big)=1
    return fmaf(-2.f, __builtin_amdgcn_rcpf(t + 1.f), 1.f);
}

#define REPEAT8(M) M(0) M(1) M(2) M(3) M(4) M(5) M(6) M(7)

// weights for k-pair (kb+2K, kb+2K+1): rows A,B x gates f,i,g,o
#define DECLW(K) v2f wAf##K, wAi##K, wAg##K, wAo##K, wBf##K, wBi##K, wBg##K, wBo##K;
#define LOADW(K) { const float* r0 = wmat + (size_t)(kb + 2*(K)) * G4; \
                   const float* r1 = r0 + G4; \
                   wAf##K = mkv2(r0[rA],          r1[rA]); \
                   wAi##K = mkv2(r0[H_ + rA],     r1[H_ + rA]); \
                   wAg##K = mkv2(r0[2*H_ + rA],   r1[2*H_ + rA]); \
                   wAo##K = mkv2(r0[3*H_ + rA],   r1[3*H_ + rA]); \
                   wBf##K = mkv2(r0[rB],          r1[rB]); \
                   wBi##K = mkv2(r0[H_ + rB],     r1[H_ + rB]); \
                   wBg##K = mkv2(r0[2*H_ + rB],   r1[2*H_ + rB]); \
                   wBo##K = mkv2(r0[3*H_ + rB],   r1[3*H_ + rB]); }

// packed fp32 FMA: acc.xy += h2.xy * w2.xy  (VOP3P, CDNA2+)
#define PKFMA(ACC, H2, W2) asm("v_pk_fma_f32 %0, %1, %2, %0" : "+v"(ACC) : "v"(H2), "v"(W2));
#define FMAK(K, H2) { PKFMA(aAf, H2, wAf##K) PKFMA(aAi, H2, wAi##K) \
                      PKFMA(aAg, H2, wAg##K) PKFMA(aAo, H2, wAo##K) \
                      PKFMA(aBf, H2, wBf##K) PKFMA(aBi, H2, wBi##K) \
                      PKFMA(aBg, H2, wBg##K) PKFMA(aBo, H2, wBo##K) }

// ---------------- P0: token table, layout [v][4][132] ----------------
__global__ __launch_bounds__(G4)
void build_table0(const float* __restrict__ emb,
                  const float* __restrict__ wx0,
                  const float* __restrict__ b0,
                  float* __restrict__ table0)
{
    const int v = blockIdx.x;        // 0..26
    const int j = threadIdx.x;       // col 0..511
    __shared__ float e[E_];
    if (j < E_) e[j] = emb[v * E_ + j];
    __syncthreads();
    float s = b0[j];
#pragma unroll 8
    for (int k = 0; k < E_; ++k) s += e[k] * wx0[k * G4 + j];
    const int r = j & (H_ - 1), gate = j >> 7;
    table0[v * TPITCH + gate * 132 + r] = s;
}

// ---------------- P1: layer-0 recurrence (row-pair x k-eighth) ----------------
__global__ __launch_bounds__(512, 2)
void lstm_l0_chunk(const int* __restrict__ x,
                   const float* __restrict__ table0,
                   const float* __restrict__ wh0,
                   float* __restrict__ h0st, float* __restrict__ c0st,
                   float* __restrict__ h0buf,
                   int t0, int TC)
{
    const int j  = threadIdx.x;       // 0..511
    const int rg = j >> 3;            // row-pair 0..63
    const int q  = j & 7;             // combo index / k-eighth
    const int b  = blockIdx.x;
    const int kb = 16 * q;
    const int rA = 2 * rg, rB = 2 * rg + 1;
    const int g  = q & 3;             // gate of this lane's combo
    const int rr = 2 * rg + (q >> 2); // row of this lane's combo

    __shared__ __align__(16) float hP[2][8][20];   // h[16a+m] at [a][m]; pitch 20 -> conflict-free

    const float* wmat = wh0;
    REPEAT8(DECLW)
    REPEAT8(LOADW)
    if (j < H_) hP[0][j >> 4][j & 15] = h0st[b * H_ + j];
    float c = c0st[b * H_ + rr];
    float hh = 0.f;
    __syncthreads();

    const int* xb = x + (size_t)b * T_ + t0;
    float* hob = h0buf + (size_t)b * TC * H_;
    const float A = (g == 2) ? 2.f : 1.f;          // tanh for g-gate, sigmoid else
    const int toff = g * 132 + rr;
    const bool q0 = (q & 1), q1 = (q & 2), q2 = (q & 4);

    float tv = table0[xb[0] * TPITCH + toff];
    for (int t = 0; t < TC; ++t) {
        const int idxn = (t + 1 < TC) ? xb[t + 1] : 0;

        const v4f* hb4 = reinterpret_cast<const v4f*>(&hP[t & 1][q][0]);
        const v4f u0 = hb4[0], u1 = hb4[1], u2 = hb4[2], u3 = hb4[3];
        const v2f h0 = __builtin_shufflevector(u0, u0, 0, 1);
        const v2f h1 = __builtin_shufflevector(u0, u0, 2, 3);
        const v2f h2 = __builtin_shufflevector(u1, u1, 0, 1);
        const v2f h3 = __builtin_shufflevector(u1, u1, 2, 3);
        const v2f h4 = __builtin_shufflevector(u2, u2, 0, 1);
        const v2f h5 = __builtin_shufflevector(u2, u2, 2, 3);
        const v2f h6 = __builtin_shufflevector(u3, u3, 0, 1);
        const v2f h7 = __builtin_shufflevector(u3, u3, 2, 3);

        v2f aAf = mkv2(0.f, 0.f), aAi = aAf, aAg = aAf, aAo = aAf,
            aBf = aAf, aBi = aAf, aBg = aAf, aBo = aAf;
        FMAK(0, h0) FMAK(1, h1) FMAK(2, h2) FMAK(3, h3)
        FMAK(4, h4) FMAK(5, h5) FMAK(6, h6) FMAK(7, h7)

        const float sAf = sum8(aAf.x + aAf.y);
        const float sAi = sum8(aAi.x + aAi.y);
        const float sAg = sum8(aAg.x + aAg.y);
        const float sAo = sum8(aAo.x + aAo.y);
        const float sBf = sum8(aBf.x + aBf.y);
        const float sBi = sum8(aBi.x + aBi.y);
        const float sBg = sum8(aBg.x + aBg.y);
        const float sBo = sum8(aBo.x + aBo.y);

        const float s0 = q0 ? sAi : sAf;
        const float s1 = q0 ? sAo : sAg;
        const float s2 = q0 ? sBi : sBf;
        const float s3 = q0 ? sBo : sBg;
        const float s4 = q1 ? s1 : s0;
        const float s5 = q1 ? s3 : s2;
        const float val = (q2 ? s5 : s4) + tv;

        const float tz  = __expf(A * val);
        const float act = fmaf(-A, __builtin_amdgcn_rcpf(tz + 1.f), 1.f);

        const float iv = dppmov<0x39>(act);   // lane base+0 <- base+1 (i)
        const float gv = dppmov<0x4E>(act);   // <- base+2 (g)
        const float ov = dppmov<0x93>(act);   // <- base+3 (o)
        c  = fmaf(act, c, iv * gv);           // lanes q=0,4: f*c + i*g
        hh = tanh_fast(c) * ov;               // other lanes: garbage, unused

        if (g == 0) {
            hP[(t + 1) & 1][rr >> 4][rr & 15] = hh;
            hob[(size_t)t * H_ + rr] = hh;
        }
        tv = table0[idxn * TPITCH + toff];    // prefetch next step's addend (L2)
        __syncthreads();
    }
    if (g == 0) { h0st[b * H_ + rr] = hh; c0st[b * H_ + rr] = c; }
}

// ---------------- P2: xg1 = h0 @ wx1 + b1 ----------------
__global__ __launch_bounds__(G4, 2)
void gemm_xg1(const float* __restrict__ h0buf,
              const float* __restrict__ wx1,
              const float* __restrict__ b1,
              float* __restrict__ xg1)
{
    const int j  = threadIdx.x;
    const size_t m0 = (size_t)blockIdx.x * 64;
    const int c  = j & 127;          // cols c, c+128, c+256, c+384
    const int rg = j >> 7;           // rows rg*16 .. rg*16+15

    __shared__ __align__(16) float aT[64 * 132];   // row-major [r][k], pad 132

#pragma unroll
    for (int i = 0; i < 4; ++i) {
        const int e  = i * G4 + j;       // float4 index 0..2047
        const int r  = e >> 5;           // 32 float4 per row
        const int k4 = e & 31;
        const float4 v = *reinterpret_cast<const float4*>(&h0buf[(m0 + r) * H_ + k4 * 4]);
        *reinterpret_cast<float4*>(&aT[r * 132 + k4 * 4]) = v;
    }
    __syncthreads();

    float acc[4][16];
#pragma unroll
    for (int cc = 0; cc < 4; ++cc)
#pragma unroll
        for (int rr = 0; rr < 16; ++rr) acc[cc][rr] = 0.f;

    for (int k4 = 0; k4 < 32; ++k4) {
        float bv[4][4];   // [kk][cc]
#pragma unroll
        for (int kk = 0; kk < 4; ++kk)
#pragma unroll
            for (int cc = 0; cc < 4; ++cc)
                bv[kk][cc] = wx1[(size_t)(k4 * 4 + kk) * G4 + cc * 128 + c];
#pragma unroll
        for (int rr = 0; rr < 16; ++rr) {
            const float4 av = *reinterpret_cast<const float4*>(&aT[(rg * 16 + rr) * 132 + k4 * 4]);
#pragma unroll
            for (int cc = 0; cc < 4; ++cc) {
                acc[cc][rr] = fmaf(av.x, bv[0][cc], acc[cc][rr]);
                acc[cc][rr] = fmaf(av.y, bv[1][cc], acc[cc][rr]);
                acc[cc][rr] = fmaf(av.z, bv[2][cc], acc[cc][rr]);
                acc[cc][rr] = fmaf(av.w, bv[3][cc], acc[cc][rr]);
            }
        }
    }

    float b1v[4];
#pragma unroll
    for (int cc = 0; cc < 4; ++cc) b1v[cc] = b1[cc * 128 + c];
#pragma unroll
    for (int rr = 0; rr < 16; ++rr) {
        const size_t row = m0 + rg * 16 + rr;
#pragma unroll
        for (int cc = 0; cc < 4; ++cc)
            xg1[row * G4 + cc * 128 + c] = acc[cc][rr] + b1v[cc];
    }
}

// ---------------- P3: layer-1 recurrence (row-pair x k-eighth) ----------------
__global__ __launch_bounds__(512, 2)
void lstm_l1_chunk(const float* __restrict__ xg1,
                   const float* __restrict__ wh1,
                   float* __restrict__ h1st, float* __restrict__ c1st,
                   float* __restrict__ h1buf,
                   int TC)
{
    const int j  = threadIdx.x;
    const int rg = j >> 3;
    const int q  = j & 7;
    const int b  = blockIdx.x;
    const int kb = 16 * q;
    const int rA = 2 * rg, rB = 2 * rg + 1;
    const int g  = q & 3;
    const int rr = 2 * rg + (q >> 2);

    __shared__ __align__(16) float hP[2][8][20];

    const float* wmat = wh1;
    REPEAT8(DECLW)
    REPEAT8(LOADW)
    if (j < H_) hP[0][j >> 4][j & 15] = h1st[b * H_ + j];
    float c = c1st[b * H_ + rr];
    float hh = 0.f;
    __syncthreads();

    const float* xgb = xg1 + (size_t)b * TC * G4;
    float* hob = h1buf + (size_t)b * TC * H_;
    const float A = (g == 2) ? 2.f : 1.f;
    const int xcol = g * H_ + rr;
    const bool q0 = (q & 1), q1 = (q & 2), q2 = (q & 4);

    float xv = xgb[xcol];
    for (int t = 0; t < TC; ++t) {
        const float xvn = (t + 1 < TC) ? xgb[(size_t)(t + 1) * G4 + xcol] : 0.f;

        const v4f* hb4 = reinterpret_cast<const v4f*>(&hP[t & 1][q][0]);
        const v4f u0 = hb4[0], u1 = hb4[1], u2 = hb4[2], u3 = hb4[3];
        const v2f h0 = __builtin_shufflevector(u0, u0, 0, 1);
        const v2f h1 = __builtin_shufflevector(u0, u0, 2, 3);
        const v2f h2 = __builtin_shufflevector(u1, u1, 0, 1);
        const v2f h3 = __builtin_shufflevector(u1, u1, 2, 3);
        const v2f h4 = __builtin_shufflevector(u2, u2, 0, 1);
        const v2f h5 = __builtin_shufflevector(u2, u2, 2, 3);
        const v2f h6 = __builtin_shufflevector(u3, u3, 0, 1);
        const v2f h7 = __builtin_shufflevector(u3, u3, 2, 3);

        v2f aAf = mkv2(0.f, 0.f), aAi = aAf, aAg = aAf, aAo = aAf,
            aBf = aAf, aBi = aAf, aBg = aAf, aBo = aAf;
        FMAK(0, h0) FMAK(1, h1) FMAK(2, h2) FMAK(3, h3)
        FMAK(4, h4) FMAK(5, h5) FMAK(6, h6) FMAK(7, h7)

        const float sAf = sum8(aAf.x + aAf.y);
        const float sAi = sum8(aAi.x + aAi.y);
        const float sAg = sum8(aAg.x + aAg.y);
        const float sAo = sum8(aAo.x + aAo.y);
        const float sBf = sum8(aBf.x + aBf.y);
        const float sBi = sum8(aBi.x + aBi.y);
        const float sBg = sum8(aBg.x + aBg.y);
        const float sBo = sum8(aBo.x + aBo.y);

        const float s0 = q0 ? sAi : sAf;
        const float s1 = q0 ? sAo : sAg;
        const float s2 = q0 ? sBi : sBf;
        const float s3 = q0 ? sBo : sBg;
        const float s4 = q1 ? s1 : s0;
        const float s5 = q1 ? s3 : s2;
        const float val = (q2 ? s5 : s4) + xv;    // xg1 already includes b1

        const float tz  = __expf(A * val);
        const float act = fmaf(-A, __builtin_amdgcn_rcpf(tz + 1.f), 1.f);

        const float iv = dppmov<0x39>(act);
        const float gv = dppmov<0x4E>(act);
        const float ov = dppmov<0x93>(act);
        c  = fmaf(act, c, iv * gv);
        hh = tanh_fast(c) * ov;

        if (g == 0) {
            hP[(t + 1) & 1][rr >> 4][rr & 15] = hh;
            hob[(size_t)t * H_ + rr] = hh;
        }
        xv = xvn;
        __syncthreads();
    }
    if (g == 0) { h1st[b * H_ + rr] = hh; c1st[b * H_ + rr] = c; }
}

// ---------------- P4: y = h1 @ why + by ----------------
__global__ __launch_bounds__(256)
void proj_y(const float* __restrict__ h1buf,
            const float* __restrict__ why,
            const float* __restrict__ by,
            float* __restrict__ out,
            int t0, int TC)
{
    const int tid = threadIdx.x;
    const int b   = blockIdx.x;

    __shared__ __align__(16) float whyS[V_][H_];   // [v][k], broadcast-read
    __shared__ float byS[V_];
    __shared__ float yS[256][29];                  // pad 29: conflict-free stage

    for (int e = tid; e < V_ * H_; e += 256) {
        const int v = e / H_, k = e - v * H_;
        whyS[v][k] = why[k * V_ + v];
    }
    if (tid < V_) byS[tid] = by[tid];
    __syncthreads();

    const float* hb  = h1buf + (size_t)b * TC * H_;
    float* outb      = out + ((size_t)b * T_ + t0) * V_;

    for (int tt0 = 0; tt0 < TC; tt0 += 256) {
        const int tt = tt0 + tid;
        if (tt < TC) {
            float acc[V_];
#pragma unroll
            for (int v = 0; v < V_; ++v) acc[v] = byS[v];
            const float4* hr = reinterpret_cast<const float4*>(hb + (size_t)tt * H_);
#pragma unroll 4
            for (int k4 = 0; k4 < 32; ++k4) {
                const float4 hv = hr[k4];
#pragma unroll
                for (int v = 0; v < V_; ++v) {
                    const float4 wv = *reinterpret_cast<const float4*>(&whyS[v][k4 * 4]);
                    acc[v] = fmaf(hv.x, wv.x,
                             fmaf(hv.y, wv.y,
                             fmaf(hv.z, wv.z,
                             fmaf(hv.w, wv.w, acc[v]))));
                }
            }
#pragma unroll
            for (int v = 0; v < V_; ++v) yS[tid][v] = acc[v];
        }
        __syncthreads();
        const int nrow = (TC - tt0 < 256) ? (TC - tt0) : 256;
        const int n = nrow * V_;
        float* od = outb + (size_t)tt0 * V_;
        for (int i = tid; i < n; i += 256) {
            const int r = i / V_, v = i - r * V_;
            od[i] = yS[r][v];
        }
        __syncthreads();
    }
}

// ---------------- fallback: streaming kernel (uses [v][4][132] table) ----------------
__global__ __launch_bounds__(G4, 1)
void lstm_persist(const int* __restrict__ x,
                  const float* __restrict__ table0,
                  const float* __restrict__ wh0,
                  const float* __restrict__ wx1,
                  const float* __restrict__ wh1,
                  const float* __restrict__ b1,
                  const float* __restrict__ why,
                  const float* __restrict__ by,
                  float* __restrict__ out)
{
    const int j  = threadIdx.x;
    const int bb = blockIdx.x * 2;

    __shared__ float h0s[2][H_], c0s[2][H_], h1s[2][H_], c1s[2][H_];
    __shared__ float hcat[2][2 * H_];
    __shared__ float g0s[2][G4], g1s[2][G4];
    __shared__ float whyS[H_ * V_];
    __shared__ float b1S[G4];
    __shared__ float byS[V_];
    __shared__ float pb[2][V_][8];

    for (int i = j; i < H_ * V_; i += G4) whyS[i] = why[i];
    b1S[j] = b1[j];
    if (j < V_) byS[j] = by[j];
    if (j < H_) {
        h0s[0][j] = 0.f; h0s[1][j] = 0.f; c0s[0][j] = 0.f; c0s[1][j] = 0.f;
        h1s[0][j] = 0.f; h1s[1][j] = 0.f; c1s[0][j] = 0.f; c1s[1][j] = 0.f;
    }
    __syncthreads();

    const int* xA = x + (size_t)(bb + 0) * T_;
    const int* xB = x + (size_t)(bb + 1) * T_;
    float* outA = out + (size_t)(bb + 0) * T_ * V_;
    float* outB = out + (size_t)(bb + 1) * T_ * V_;

    const int tix = (j >> 7) * 132 + (j & (H_ - 1));

    for (int t = 0; t < T_; ++t) {
        const int ia = xA[t];
        const int ib = xB[t];
        float aA = table0[ia * TPITCH + tix];
        float aB = table0[ib * TPITCH + tix];
#pragma unroll 8
        for (int k = 0; k < H_; ++k) {
            const float w = wh0[k * G4 + j];
            aA += h0s[0][k] * w;
            aB += h0s[1][k] * w;
        }
        g0s[0][j] = aA; g0s[1][j] = aB;
        __syncthreads();

        if (j < 2 * H_) {
            const int gi = j >> 7, r = j & (H_ - 1);
            const float f  = 1.f / (1.f + expf(-g0s[gi][r]));
            const float i_ = 1.f / (1.f + expf(-g0s[gi][H_ + r]));
            const float g  = tanhf(g0s[gi][2 * H_ + r]);
            const float o  = 1.f / (1.f + expf(-g0s[gi][3 * H_ + r]));
            const float c  = f * c0s[gi][r] + i_ * g;
            c0s[gi][r] = c;
            const float h = tanhf(c) * o;
            h0s[gi][r] = h;
            hcat[gi][r] = h;
            hcat[gi][H_ + r] = h1s[gi][r];
        }
        __syncthreads();

        float bA = b1S[j];
        float bB = bA;
#pragma unroll 8
        for (int k = 0; k < H_; ++k) {
            const float w = wx1[k * G4 + j];
            bA += hcat[0][k] * w;
            bB += hcat[1][k] * w;
        }
#pragma unroll 8
        for (int k = 0; k < H_; ++k) {
            const float w = wh1[k * G4 + j];
            bA += hcat[0][H_ + k] * w;
            bB += hcat[1][H_ + k] * w;
        }
        g1s[0][j] = bA; g1s[1][j] = bB;
        __syncthreads();

        if (j < 2 * H_) {
            const int gi = j >> 7, r = j & (H_ - 1);
            const float f  = 1.f / (1.f + expf(-g1s[gi][r]));
            const float i_ = 1.f / (1.f + expf(-g1s[gi][H_ + r]));
            const float g  = tanhf(g1s[gi][2 * H_ + r]);
            const float o  = 1.f / (1.f + expf(-g1s[gi][3 * H_ + r]));
            const float c  = f * c1s[gi][r] + i_ * g;
            c1s[gi][r] = c;
            h1s[gi][r] = tanhf(c) * o;
        }
        __syncthreads();

        if (j < 2 * V_ * 8) {
            int qq = j;
            const int gi = (qq >= V_ * 8) ? 1 : 0;
            qq -= gi * V_ * 8;
            const int v = qq >> 3, kk = qq & 7;
            float pv = 0.f;
#pragma unroll
            for (int k = kk * 16; k < kk * 16 + 16; ++k)
                pv += h1s[gi][k] * whyS[k * V_ + v];
            pb[gi][v][kk] = pv;
        }
        __syncthreads();

        if (j < 2 * V_) {
            const int gi = (j >= V_) ? 1 : 0;
            const int v  = j - gi * V_;
            float s = byS[v];
#pragma unroll
            for (int qq = 0; qq < 8; ++qq) s += pb[gi][v][qq];
            (gi ? outB : outA)[t * V_ + v] = s;
        }
        __syncthreads();
    }
}

// ---------------- host ----------------
extern "C" void kernel_launch(void* const* d_in, const int* in_sizes, int n_in,
                              void* d_out, int out_size, void* d_ws, size_t ws_size,
                              hipStream_t stream)
{
    const int*   x   = (const int*)  d_in[0];
    const float* emb = (const float*)d_in[1];
    const float* wx0 = (const float*)d_in[2];
    const float* wh0 = (const float*)d_in[3];
    const float* b0  = (const float*)d_in[4];
    const float* wx1 = (const float*)d_in[5];
    const float* wh1 = (const float*)d_in[6];
    const float* b1  = (const float*)d_in[7];
    const float* why = (const float*)d_in[8];
    const float* by  = (const float*)d_in[9];
    float* out = (float*)d_out;
    float* wsf = (float*)d_ws;

    const size_t tabF   = (size_t)V_ * TPITCH;   // 14256 floats
    const size_t stateF = (size_t)4 * B_ * H_;   // 131072 floats

    int TC = 0;
    for (int tc = T_; tc >= 32; tc >>= 1) {
        // per-chunk buffers: h0buf (H) + xg1buf (G4) + h1buf (H) per (b,t)
        const size_t need = (tabF + stateF + (size_t)B_ * tc * (H_ + G4 + H_)) * 4;
        if (need <= ws_size) { TC = tc; break; }
    }

    float* table0 = wsf;
    build_table0<<<dim3(V_), dim3(G4), 0, stream>>>(emb, wx0, b0, table0);

    if (TC == 0) {
        lstm_persist<<<dim3(B_ / 2), dim3(G4), 0, stream>>>(
            x, table0, wh0, wx1, wh1, b1, why, by, out);
        return;
    }

    float* h0st   = wsf + tabF;
    float* c0st   = h0st + (size_t)B_ * H_;
    float* h1st   = c0st + (size_t)B_ * H_;
    float* c1st   = h1st + (size_t)B_ * H_;
    float* h0buf  = c1st + (size_t)B_ * H_;
    float* xg1buf = h0buf + (size_t)B_ * TC * H_;
    float* h1buf  = xg1buf + (size_t)B_ * TC * G4;

    (void)hipMemsetAsync(h0st, 0, stateF * sizeof(float), stream);

    const int NC = T_ / TC;
    for (int c = 0; c < NC; ++c) {
        const int t0 = c * TC;
        lstm_l0_chunk<<<dim3(B_), dim3(512), 0, stream>>>(
            x, table0, wh0, h0st, c0st, h0buf, t0, TC);
        gemm_xg1<<<dim3(4 * TC), dim3(G4), 0, stream>>>(
            h0buf, wx1, b1, xg1buf);
        lstm_l1_chunk<<<dim3(B_), dim3(512), 0, stream>>>(
            xg1buf, wh1, h1st, c1st, h1buf, TC);
        proj_y<<<dim3(B_), dim3(256), 0, stream>>>(
            h1buf, why, by, out, t0, TC);
    }
}

// Round 13
// 2086.851 us; speedup vs baseline: 1.0211x; 1.0211x over previous
//
#include <hip/hip_runtime.h>

// MultiLayerLSTM: B=256, T=1024, V=27, E=64, H=128 (4H=512)
// Round 13: 16-wave recurrence blocks + lean tail (the untested combo).
//   r11 (8 waves, lean): 48% idle - 2 lockstep waves/SIMD can't hide the
//   per-step serial chain. r8 (16 waves, fat): 95.8% VALUBusy, zero idle,
//   but fat libm tail. This round: 1024 thr, thread=(row, k-eighth),
//   64 named weight scalars, 4x ds_read_b128 ([8][20] verified layout),
//   sum8 reduce (r8-verified), r11/r12-verified lean tail (3-cndmask gate
//   select, unified act, DPP gather, lane-local cell), L2-prefetched addend.
// Phases: P0 table, P1 l0, P2 GEMM xg1=h0@wx1+b1, P3 l1, P4 proj_y.

#define B_  256
#define T_  1024
#define V_  27
#define E_  64
#define H_  128
#define G4  512     // 4*H
#define TPITCH 528  // 4*132 padded table pitch per vocab entry

template <int CTRL>
__device__ __forceinline__ float dppmov(float v) {
    return __int_as_float(__builtin_amdgcn_update_dpp(
               0, __float_as_int(v), CTRL, 0xF, 0xF, true));
}
// all-reduce sum over aligned 8-lane group (xor1, xor2, half-row mirror)
__device__ __forceinline__ float sum8(float v) {
    v += dppmov<0xB1>(v);
    v += dppmov<0x4E>(v);
    v += dppmov<0x141>(v);
    return v;
}
__device__ __forceinline__ float tanh_fast(float y) {
    const float t = __expf(2.f * y);             // inf-safe: tanh(+big)=1
    return fmaf(-2.f, __builtin_amdgcn_rcpf(t + 1.f), 1.f);
}

#define REPEAT16(M) M(0) M(1) M(2) M(3) M(4) M(5) M(6) M(7) \
                    M(8) M(9) M(10) M(11) M(12) M(13) M(14) M(15)

// weights for k-row (16e+K), 4 gate-columns of row p
#define DECLW(K) float wf##K, wi##K, wg##K, wo##K;
#define LOADW(K) wf##K = wrow[(size_t)(K)*G4 + p]; \
                 wi##K = wrow[(size_t)(K)*G4 + H_ + p]; \
                 wg##K = wrow[(size_t)(K)*G4 + 2*H_ + p]; \
                 wo##K = wrow[(size_t)(K)*G4 + 3*H_ + p];
#define FMAK(K, HV, C) sf = fmaf(HV.C, wf##K, sf); \
                       si = fmaf(HV.C, wi##K, si); \
                       sg_ = fmaf(HV.C, wg##K, sg_); \
                       so = fmaf(HV.C, wo##K, so);

// ---------------- P0: token table, layout [v][4][132] ----------------
__global__ __launch_bounds__(G4)
void build_table0(const float* __restrict__ emb,
                  const float* __restrict__ wx0,
                  const float* __restrict__ b0,
                  float* __restrict__ table0)
{
    const int v = blockIdx.x;        // 0..26
    const int j = threadIdx.x;       // col 0..511
    __shared__ float e[E_];
    if (j < E_) e[j] = emb[v * E_ + j];
    __syncthreads();
    float s = b0[j];
#pragma unroll 8
    for (int k = 0; k < E_; ++k) s += e[k] * wx0[k * G4 + j];
    const int r = j & (H_ - 1), gate = j >> 7;
    table0[v * TPITCH + gate * 132 + r] = s;
}

// ---------------- P1: layer-0 recurrence (row x k-eighth, 16 waves) ----------------
__global__ __launch_bounds__(1024, 4)
void lstm_l0_chunk(const int* __restrict__ x,
                   const float* __restrict__ table0,
                   const float* __restrict__ wh0,
                   float* __restrict__ h0st, float* __restrict__ c0st,
                   float* __restrict__ h0buf,
                   int t0, int TC)
{
    const int j = threadIdx.x;        // 0..1023
    const int p = j >> 3;             // row 0..127
    const int e = j & 7;              // k-eighth
    const int b = blockIdx.x;
    const int gate = e & 3;

    __shared__ __align__(16) float hP[2][8][20];   // h[16a+m] at [a][m]; conflict-free

    const float* wrow = wh0 + (size_t)(16 * e) * G4;
    REPEAT16(DECLW)
    REPEAT16(LOADW)
    if (j < H_) hP[0][j >> 4][j & 15] = h0st[b * H_ + j];
    float c = c0st[b * H_ + p];
    float hh = 0.f;
    __syncthreads();

    const int* xb = x + (size_t)b * T_ + t0;
    float* hob = h0buf + (size_t)b * TC * H_;
    const float A = (gate == 2) ? 2.f : 1.f;       // tanh for g-gate
    const int toff = gate * 132 + p;
    const bool e0 = (e & 1), e1 = (e & 2);

    float tv = table0[xb[0] * TPITCH + toff];
    for (int t = 0; t < TC; ++t) {
        const int idxn = (t + 1 < TC) ? xb[t + 1] : 0;

        const float4* hb4 = reinterpret_cast<const float4*>(&hP[t & 1][e][0]);
        const float4 h0v = hb4[0], h1v = hb4[1], h2v = hb4[2], h3v = hb4[3];

        float sf = 0.f, si = 0.f, sg_ = 0.f, so = 0.f;
        FMAK(0,  h0v, x) FMAK(1,  h0v, y) FMAK(2,  h0v, z) FMAK(3,  h0v, w)
        FMAK(4,  h1v, x) FMAK(5,  h1v, y) FMAK(6,  h1v, z) FMAK(7,  h1v, w)
        FMAK(8,  h2v, x) FMAK(9,  h2v, y) FMAK(10, h2v, z) FMAK(11, h2v, w)
        FMAK(12, h3v, x) FMAK(13, h3v, y) FMAK(14, h3v, z) FMAK(15, h3v, w)

        const float rf = sum8(sf);
        const float ri = sum8(si);
        const float rg = sum8(sg_);
        const float ro = sum8(so);

        const float s0 = e0 ? ri : rf;
        const float s1 = e0 ? ro : rg;
        const float val = (e1 ? s1 : s0) + tv;

        const float tz  = __expf(A * val);
        const float act = fmaf(-A, __builtin_amdgcn_rcpf(tz + 1.f), 1.f);

        const float iv = dppmov<0x39>(act);   // lane base+0 <- base+1 (i)
        const float gv = dppmov<0x4E>(act);   // <- base+2 (g)
        const float ov = dppmov<0x93>(act);   // <- base+3 (o)
        c  = fmaf(act, c, iv * gv);           // lanes e=0 (and 4): f*c + i*g
        hh = tanh_fast(c) * ov;               // other lanes: garbage, unused

        if (e == 0) {
            hP[(t + 1) & 1][p >> 4][p & 15] = hh;
            hob[(size_t)t * H_ + p] = hh;
        }
        tv = table0[idxn * TPITCH + toff];    // prefetch next addend (L2)
        __syncthreads();
    }
    if (e == 0) { h0st[b * H_ + p] = hh; c0st[b * H_ + p] = c; }
}

// ---------------- P2: xg1 = h0 @ wx1 + b1 ----------------
__global__ __launch_bounds__(G4, 2)
void gemm_xg1(const float* __restrict__ h0buf,
              const float* __restrict__ wx1,
              const float* __restrict__ b1,
              float* __restrict__ xg1)
{
    const int j  = threadIdx.x;
    const size_t m0 = (size_t)blockIdx.x * 64;
    const int c  = j & 127;          // cols c, c+128, c+256, c+384
    const int rg = j >> 7;           // rows rg*16 .. rg*16+15

    __shared__ __align__(16) float aT[64 * 132];   // row-major [r][k], pad 132

#pragma unroll
    for (int i = 0; i < 4; ++i) {
        const int e  = i * G4 + j;       // float4 index 0..2047
        const int r  = e >> 5;           // 32 float4 per row
        const int k4 = e & 31;
        const float4 v = *reinterpret_cast<const float4*>(&h0buf[(m0 + r) * H_ + k4 * 4]);
        *reinterpret_cast<float4*>(&aT[r * 132 + k4 * 4]) = v;
    }
    __syncthreads();

    float acc[4][16];
#pragma unroll
    for (int cc = 0; cc < 4; ++cc)
#pragma unroll
        for (int rr = 0; rr < 16; ++rr) acc[cc][rr] = 0.f;

    for (int k4 = 0; k4 < 32; ++k4) {
        float bv[4][4];   // [kk][cc]
#pragma unroll
        for (int kk = 0; kk < 4; ++kk)
#pragma unroll
            for (int cc = 0; cc < 4; ++cc)
                bv[kk][cc] = wx1[(size_t)(k4 * 4 + kk) * G4 + cc * 128 + c];
#pragma unroll
        for (int rr = 0; rr < 16; ++rr) {
            const float4 av = *reinterpret_cast<const float4*>(&aT[(rg * 16 + rr) * 132 + k4 * 4]);
#pragma unroll
            for (int cc = 0; cc < 4; ++cc) {
                acc[cc][rr] = fmaf(av.x, bv[0][cc], acc[cc][rr]);
                acc[cc][rr] = fmaf(av.y, bv[1][cc], acc[cc][rr]);
                acc[cc][rr] = fmaf(av.z, bv[2][cc], acc[cc][rr]);
                acc[cc][rr] = fmaf(av.w, bv[3][cc], acc[cc][rr]);
            }
        }
    }

    float b1v[4];
#pragma unroll
    for (int cc = 0; cc < 4; ++cc) b1v[cc] = b1[cc * 128 + c];
#pragma unroll
    for (int rr = 0; rr < 16; ++rr) {
        const size_t row = m0 + rg * 16 + rr;
#pragma unroll
        for (int cc = 0; cc < 4; ++cc)
            xg1[row * G4 + cc * 128 + c] = acc[cc][rr] + b1v[cc];
    }
}

// ---------------- P3: layer-1 recurrence (row x k-eighth, 16 waves) ----------------
__global__ __launch_bounds__(1024, 4)
void lstm_l1_chunk(const float* __restrict__ xg1,
                   const float* __restrict__ wh1,
                   float* __restrict__ h1st, float* __restrict__ c1st,
                   float* __restrict__ h1buf,
                   int TC)
{
    const int j = threadIdx.x;
    const int p = j >> 3;
    const int e = j & 7;
    const int b = blockIdx.x;
    const int gate = e & 3;

    __shared__ __align__(16) float hP[2][8][20];

    const float* wrow = wh1 + (size_t)(16 * e) * G4;
    REPEAT16(DECLW)
    REPEAT16(LOADW)
    if (j < H_) hP[0][j >> 4][j & 15] = h1st[b * H_ + j];
    float c = c1st[b * H_ + p];
    float hh = 0.f;
    __syncthreads();

    const float* xgb = xg1 + (size_t)b * TC * G4;
    float* hob = h1buf + (size_t)b * TC * H_;
    const float A = (gate == 2) ? 2.f : 1.f;
    const int xcol = gate * H_ + p;
    const bool e0 = (e & 1), e1 = (e & 2);

    float xv = xgb[xcol];
    for (int t = 0; t < TC; ++t) {
        const float xvn = (t + 1 < TC) ? xgb[(size_t)(t + 1) * G4 + xcol] : 0.f;

        const float4* hb4 = reinterpret_cast<const float4*>(&hP[t & 1][e][0]);
        const float4 h0v = hb4[0], h1v = hb4[1], h2v = hb4[2], h3v = hb4[3];

        float sf = 0.f, si = 0.f, sg_ = 0.f, so = 0.f;
        FMAK(0,  h0v, x) FMAK(1,  h0v, y) FMAK(2,  h0v, z) FMAK(3,  h0v, w)
        FMAK(4,  h1v, x) FMAK(5,  h1v, y) FMAK(6,  h1v, z) FMAK(7,  h1v, w)
        FMAK(8,  h2v, x) FMAK(9,  h2v, y) FMAK(10, h2v, z) FMAK(11, h2v, w)
        FMAK(12, h3v, x) FMAK(13, h3v, y) FMAK(14, h3v, z) FMAK(15, h3v, w)

        const float rf = sum8(sf);
        const float ri = sum8(si);
        const float rg = sum8(sg_);
        const float ro = sum8(so);

        const float s0 = e0 ? ri : rf;
        const float s1 = e0 ? ro : rg;
        const float val = (e1 ? s1 : s0) + xv;    // xg1 already includes b1

        const float tz  = __expf(A * val);
        const float act = fmaf(-A, __builtin_amdgcn_rcpf(tz + 1.f), 1.f);

        const float iv = dppmov<0x39>(act);
        const float gv = dppmov<0x4E>(act);
        const float ov = dppmov<0x93>(act);
        c  = fmaf(act, c, iv * gv);
        hh = tanh_fast(c) * ov;

        if (e == 0) {
            hP[(t + 1) & 1][p >> 4][p & 15] = hh;
            hob[(size_t)t * H_ + p] = hh;
        }
        xv = xvn;
        __syncthreads();
    }
    if (e == 0) { h1st[b * H_ + p] = hh; c1st[b * H_ + p] = c; }
}

// ---------------- P4: y = h1 @ why + by ----------------
__global__ __launch_bounds__(256)
void proj_y(const float* __restrict__ h1buf,
            const float* __restrict__ why,
            const float* __restrict__ by,
            float* __restrict__ out,
            int t0, int TC)
{
    const int tid = threadIdx.x;
    const int b   = blockIdx.x;

    __shared__ __align__(16) float whyS[V_][H_];   // [v][k], broadcast-read
    __shared__ float byS[V_];
    __shared__ float yS[256][29];                  // pad 29: conflict-free stage

    for (int e = tid; e < V_ * H_; e += 256) {
        const int v = e / H_, k = e - v * H_;
        whyS[v][k] = why[k * V_ + v];
    }
    if (tid < V_) byS[tid] = by[tid];
    __syncthreads();

    const float* hb  = h1buf + (size_t)b * TC * H_;
    float* outb      = out + ((size_t)b * T_ + t0) * V_;

    for (int tt0 = 0; tt0 < TC; tt0 += 256) {
        const int tt = tt0 + tid;
        if (tt < TC) {
            float acc[V_];
#pragma unroll
            for (int v = 0; v < V_; ++v) acc[v] = byS[v];
            const float4* hr = reinterpret_cast<const float4*>(hb + (size_t)tt * H_);
#pragma unroll 4
            for (int k4 = 0; k4 < 32; ++k4) {
                const float4 hv = hr[k4];
#pragma unroll
                for (int v = 0; v < V_; ++v) {
                    const float4 wv = *reinterpret_cast<const float4*>(&whyS[v][k4 * 4]);
                    acc[v] = fmaf(hv.x, wv.x,
                             fmaf(hv.y, wv.y,
                             fmaf(hv.z, wv.z,
                             fmaf(hv.w, wv.w, acc[v]))));
                }
            }
#pragma unroll
            for (int v = 0; v < V_; ++v) yS[tid][v] = acc[v];
        }
        __syncthreads();
        const int nrow = (TC - tt0 < 256) ? (TC - tt0) : 256;
        const int n = nrow * V_;
        float* od = outb + (size_t)tt0 * V_;
        for (int i = tid; i < n; i += 256) {
            const int r = i / V_, v = i - r * V_;
            od[i] = yS[r][v];
        }
        __syncthreads();
    }
}

// ---------------- fallback: streaming kernel (uses [v][4][132] table) ----------------
__global__ __launch_bounds__(G4, 1)
void lstm_persist(const int* __restrict__ x,
                  const float* __restrict__ table0,
                  const float* __restrict__ wh0,
                  const float* __restrict__ wx1,
                  const float* __restrict__ wh1,
                  const float* __restrict__ b1,
                  const float* __restrict__ why,
                  const float* __restrict__ by,
                  float* __restrict__ out)
{
    const int j  = threadIdx.x;
    const int bb = blockIdx.x * 2;

    __shared__ float h0s[2][H_], c0s[2][H_], h1s[2][H_], c1s[2][H_];
    __shared__ float hcat[2][2 * H_];
    __shared__ float g0s[2][G4], g1s[2][G4];
    __shared__ float whyS[H_ * V_];
    __shared__ float b1S[G4];
    __shared__ float byS[V_];
    __shared__ float pb[2][V_][8];

    for (int i = j; i < H_ * V_; i += G4) whyS[i] = why[i];
    b1S[j] = b1[j];
    if (j < V_) byS[j] = by[j];
    if (j < H_) {
        h0s[0][j] = 0.f; h0s[1][j] = 0.f; c0s[0][j] = 0.f; c0s[1][j] = 0.f;
        h1s[0][j] = 0.f; h1s[1][j] = 0.f; c1s[0][j] = 0.f; c1s[1][j] = 0.f;
    }
    __syncthreads();

    const int* xA = x + (size_t)(bb + 0) * T_;
    const int* xB = x + (size_t)(bb + 1) * T_;
    float* outA = out + (size_t)(bb + 0) * T_ * V_;
    float* outB = out + (size_t)(bb + 1) * T_ * V_;

    const int tix = (j >> 7) * 132 + (j & (H_ - 1));

    for (int t = 0; t < T_; ++t) {
        const int ia = xA[t];
        const int ib = xB[t];
        float aA = table0[ia * TPITCH + tix];
        float aB = table0[ib * TPITCH + tix];
#pragma unroll 8
        for (int k = 0; k < H_; ++k) {
            const float w = wh0[k * G4 + j];
            aA += h0s[0][k] * w;
            aB += h0s[1][k] * w;
        }
        g0s[0][j] = aA; g0s[1][j] = aB;
        __syncthreads();

        if (j < 2 * H_) {
            const int gi = j >> 7, r = j & (H_ - 1);
            const float f  = 1.f / (1.f + expf(-g0s[gi][r]));
            const float i_ = 1.f / (1.f + expf(-g0s[gi][H_ + r]));
            const float g  = tanhf(g0s[gi][2 * H_ + r]);
            const float o  = 1.f / (1.f + expf(-g0s[gi][3 * H_ + r]));
            const float c  = f * c0s[gi][r] + i_ * g;
            c0s[gi][r] = c;
            const float h = tanhf(c) * o;
            h0s[gi][r] = h;
            hcat[gi][r] = h;
            hcat[gi][H_ + r] = h1s[gi][r];
        }
        __syncthreads();

        float bA = b1S[j];
        float bB = bA;
#pragma unroll 8
        for (int k = 0; k < H_; ++k) {
            const float w = wx1[k * G4 + j];
            bA += hcat[0][k] * w;
            bB += hcat[1][k] * w;
        }
#pragma unroll 8
        for (int k = 0; k < H_; ++k) {
            const float w = wh1[k * G4 + j];
            bA += hcat[0][H_ + k] * w;
            bB += hcat[1][H_ + k] * w;
        }
        g1s[0][j] = bA; g1s[1][j] = bB;
        __syncthreads();

        if (j < 2 * H_) {
            const int gi = j >> 7, r = j & (H_ - 1);
            const float f  = 1.f / (1.f + expf(-g1s[gi][r]));
            const float i_ = 1.f / (1.f + expf(-g1s[gi][H_ + r]));
            const float g  = tanhf(g1s[gi][2 * H_ + r]);
            const float o  = 1.f / (1.f + expf(-g1s[gi][3 * H_ + r]));
            const float c  = f * c1s[gi][r] + i_ * g;
            c1s[gi][r] = c;
            h1s[gi][r] = tanhf(c) * o;
        }
        __syncthreads();

        if (j < 2 * V_ * 8) {
            int qq = j;
            const int gi = (qq >= V_ * 8) ? 1 : 0;
            qq -= gi * V_ * 8;
            const int v = qq >> 3, kk = qq & 7;
            float pv = 0.f;
#pragma unroll
            for (int k = kk * 16; k < kk * 16 + 16; ++k)
                pv += h1s[gi][k] * whyS[k * V_ + v];
            pb[gi][v][kk] = pv;
        }
        __syncthreads();

        if (j < 2 * V_) {
            const int gi = (j >= V_) ? 1 : 0;
            const int v  = j - gi * V_;
            float s = byS[v];
#pragma unroll
            for (int qq = 0; qq < 8; ++qq) s += pb[gi][v][qq];
            (gi ? outB : outA)[t * V_ + v] = s;
        }
        __syncthreads();
    }
}

// ---------------- host ----------------
extern "C" void kernel_launch(void* const* d_in, const int* in_sizes, int n_in,
                              void* d_out, int out_size, void* d_ws, size_t ws_size,
                              hipStream_t stream)
{
    const int*   x   = (const int*)  d_in[0];
    const float* emb = (const float*)d_in[1];
    const float* wx0 = (const float*)d_in[2];
    const float* wh0 = (const float*)d_in[3];
    const float* b0  = (const float*)d_in[4];
    const float* wx1 = (const float*)d_in[5];
    const float* wh1 = (const float*)d_in[6];
    const float* b1  = (const float*)d_in[7];
    const float* why = (const float*)d_in[8];
    const float* by  = (const float*)d_in[9];
    float* out = (float*)d_out;
    float* wsf = (float*)d_ws;

    const size_t tabF   = (size_t)V_ * TPITCH;   // 14256 floats
    const size_t stateF = (size_t)4 * B_ * H_;   // 131072 floats

    int TC = 0;
    for (int tc = T_; tc >= 32; tc >>= 1) {
        // per-chunk buffers: h0buf (H) + xg1buf (G4) + h1buf (H) per (b,t)
        const size_t need = (tabF + stateF + (size_t)B_ * tc * (H_ + G4 + H_)) * 4;
        if (need <= ws_size) { TC = tc; break; }
    }

    float* table0 = wsf;
    build_table0<<<dim3(V_), dim3(G4), 0, stream>>>(emb, wx0, b0, table0);

    if (TC == 0) {
        lstm_persist<<<dim3(B_ / 2), dim3(G4), 0, stream>>>(
            x, table0, wh0, wx1, wh1, b1, why, by, out);
        return;
    }

    float* h0st   = wsf + tabF;
    float* c0st   = h0st + (size_t)B_ * H_;
    float* h1st   = c0st + (size_t)B_ * H_;
    float* c1st   = h1st + (size_t)B_ * H_;
    float* h0buf  = c1st + (size_t)B_ * H_;
    float* xg1buf = h0buf + (size_t)B_ * TC * H_;
    float* h1buf  = xg1buf + (size_t)B_ * TC * G4;

    (void)hipMemsetAsync(h0st, 0, stateF * sizeof(float), stream);

    const int NC = T_ / TC;
    for (int c = 0; c < NC; ++c) {
        const int t0 = c * TC;
        lstm_l0_chunk<<<dim3(B_), dim3(1024), 0, stream>>>(
            x, table0, wh0, h0st, c0st, h0buf, t0, TC);
        gemm_xg1<<<dim3(4 * TC), dim3(G4), 0, stream>>>(
            h0buf, wx1, b1, xg1buf);
        lstm_l1_chunk<<<dim3(B_), dim3(1024), 0, stream>>>(
            xg1buf, wh1, h1st, c1st, h1buf, TC);
        proj_y<<<dim3(B_), dim3(256), 0, stream>>>(
            h1buf, why, by, out, t0, TC);
    }
}

// Round 15
// 1999.805 us; speedup vs baseline: 1.0655x; 1.0435x over previous
//
#include <hip/hip_runtime.h>

// MultiLayerLSTM: B=256, T=1024, V=27, E=64, H=128 (4H=512)
// Round 15: r14 (8 cols/thread, halved LDS h-traffic) with the DPP gather
// bug fixed. r14 used row_shr:2/4/6 which reads from LOWER lanes (shfl_up
// direction) -> consumers got 0 -> wrong output. Fix: combo map
// m = (rowparity<<2)|gate puts one row's 4 gates on consecutive lanes in a
// quad, so the cell gathers are the VERIFIED quad_perm controls 0x39/0x4E/
// 0x93 (r9-r13), consumers s in {0,4}.
//   thread = (row-pair-oct o, k-eighth s): 8 cols x 16 k = 128 weights,
//   16 h/thread via 4 conflict-free b128 from [2][8][36]; 8x sum8 reduce
//   (r8-verified) + 7-cndmask 1-of-8 select; addends global-prefetched.
// Phases: P0 table, P1 l0, P2 GEMM xg1=h0@wx1+b1, P3 l1, P4 proj_y.

#define B_  256
#define T_  1024
#define V_  27
#define E_  64
#define H_  128
#define G4  512     // 4*H
#define TPITCH 528  // 4*132 padded table pitch per vocab entry

template <int CTRL>
__device__ __forceinline__ float dppmov(float v) {
    return __int_as_float(__builtin_amdgcn_update_dpp(
               0, __float_as_int(v), CTRL, 0xF, 0xF, true));
}
// all-reduce sum over aligned 8-lane group (xor1, xor2, half-row mirror)
__device__ __forceinline__ float sum8(float v) {
    v += dppmov<0xB1>(v);
    v += dppmov<0x4E>(v);
    v += dppmov<0x141>(v);
    return v;
}
__device__ __forceinline__ float tanh_fast(float y) {
    const float t = __expf(2.f * y);             // inf-safe: tanh(+big)=1
    return fmaf(-2.f, __builtin_amdgcn_rcpf(t + 1.f), 1.f);
}

#define REPEAT16(M) M(0) M(1) M(2) M(3) M(4) M(5) M(6) M(7) \
                    M(8) M(9) M(10) M(11) M(12) M(13) M(14) M(15)

// weights for k-row (16s+K), 8 cols m = (dr<<2)|gate: col = gate*128+2o+dr
#define DECLW(K) float w0_##K, w1_##K, w2_##K, w3_##K, w4_##K, w5_##K, w6_##K, w7_##K;
#define LOADW(K) { const float* r0 = wmat + (size_t)(16 * s + (K)) * G4 + 2 * o; \
                   w0_##K = r0[0];          w1_##K = r0[H_]; \
                   w2_##K = r0[2 * H_];     w3_##K = r0[3 * H_]; \
                   w4_##K = r0[1];          w5_##K = r0[H_ + 1]; \
                   w6_##K = r0[2 * H_ + 1]; w7_##K = r0[3 * H_ + 1]; }
#define FMAK(K, HVAL) { const float hv_ = (HVAL); \
    a0 = fmaf(hv_, w0_##K, a0); a1 = fmaf(hv_, w1_##K, a1); \
    a2 = fmaf(hv_, w2_##K, a2); a3 = fmaf(hv_, w3_##K, a3); \
    a4 = fmaf(hv_, w4_##K, a4); a5 = fmaf(hv_, w5_##K, a5); \
    a6 = fmaf(hv_, w6_##K, a6); a7 = fmaf(hv_, w7_##K, a7); }

// ---------------- P0: token table, layout [v][4][132] ----------------
__global__ __launch_bounds__(G4)
void build_table0(const float* __restrict__ emb,
                  const float* __restrict__ wx0,
                  const float* __restrict__ b0,
                  float* __restrict__ table0)
{
    const int v = blockIdx.x;        // 0..26
    const int j = threadIdx.x;       // col 0..511
    __shared__ float e[E_];
    if (j < E_) e[j] = emb[v * E_ + j];
    __syncthreads();
    float sacc = b0[j];
#pragma unroll 8
    for (int k = 0; k < E_; ++k) sacc = fmaf(e[k], wx0[k * G4 + j], sacc);
    const int r = j & (H_ - 1), gate = j >> 7;
    table0[v * TPITCH + gate * 132 + r] = sacc;
}

// ---------------- P1: layer-0 recurrence (oct x k-eighth) ----------------
__global__ __launch_bounds__(512, 2)
void lstm_l0_chunk(const int* __restrict__ x,
                   const float* __restrict__ table0,
                   const float* __restrict__ wh0,
                   float* __restrict__ h0st, float* __restrict__ c0st,
                   float* __restrict__ h0buf,
                   int t0, int TC)
{
    const int j = threadIdx.x;        // 0..511
    const int o = j >> 3;             // row-pair oct 0..63 (rows 2o, 2o+1)
    const int s = j & 7;              // k-eighth AND combo index
    const int b = blockIdx.x;
    const int gl = s & 3;             // this lane's gate (f,i,g,o)
    const int rowL = 2 * o + (s >> 2);// this lane's row

    __shared__ __align__(16) float hP[2][8][36];   // h[16a+m] at [a][m]

    const float* wmat = wh0;
    REPEAT16(DECLW)
    REPEAT16(LOADW)
    if (j < H_) hP[0][j >> 4][j & 15] = h0st[b * H_ + j];
    float c = c0st[b * H_ + rowL];
    float hh = 0.f;
    __syncthreads();

    const int* xb = x + (size_t)b * T_ + t0;
    float* hob = h0buf + (size_t)b * TC * H_;
    const float A = (gl == 2) ? 2.f : 1.f;         // tanh for g-gate
    const int toff = gl * 132 + rowL;
    const bool s0 = (s & 1), s1 = (s & 2), s2 = (s & 4);

    float tv = table0[xb[0] * TPITCH + toff];
    for (int t = 0; t < TC; ++t) {
        const int idxn = (t + 1 < TC) ? xb[t + 1] : 0;

        const float4* hb4 = reinterpret_cast<const float4*>(&hP[t & 1][s][0]);
        const float4 u0 = hb4[0], u1 = hb4[1], u2 = hb4[2], u3 = hb4[3];

        float a0 = 0.f, a1 = 0.f, a2 = 0.f, a3 = 0.f,
              a4 = 0.f, a5 = 0.f, a6 = 0.f, a7 = 0.f;
        FMAK(0,  u0.x) FMAK(1,  u0.y) FMAK(2,  u0.z) FMAK(3,  u0.w)
        FMAK(4,  u1.x) FMAK(5,  u1.y) FMAK(6,  u1.z) FMAK(7,  u1.w)
        FMAK(8,  u2.x) FMAK(9,  u2.y) FMAK(10, u2.z) FMAK(11, u2.w)
        FMAK(12, u3.x) FMAK(13, u3.y) FMAK(14, u3.z) FMAK(15, u3.w)

        a0 = sum8(a0); a1 = sum8(a1); a2 = sum8(a2); a3 = sum8(a3);
        a4 = sum8(a4); a5 = sum8(a5); a6 = sum8(a6); a7 = sum8(a7);

        // lane s takes combo m == s (1-of-8 select, 7 cndmask)
        const float t0_ = s0 ? a1 : a0;
        const float t1_ = s0 ? a3 : a2;
        const float t2_ = s0 ? a5 : a4;
        const float t3_ = s0 ? a7 : a6;
        const float u0_ = s1 ? t1_ : t0_;
        const float u1_ = s1 ? t3_ : t2_;
        const float val = (s2 ? u1_ : u0_) + tv;

        const float tz  = __expf(A * val);
        const float act = fmaf(-A, __builtin_amdgcn_rcpf(tz + 1.f), 1.f);

        // one row's gates f,i,g,o sit on consecutive lanes of a quad:
        // verified quad_perm gathers (r9-r13): lane base+0 <- +1, +2, +3
        const float iv = dppmov<0x39>(act);
        const float gv = dppmov<0x4E>(act);
        const float ov = dppmov<0x93>(act);
        c  = fmaf(act, c, iv * gv);            // lanes s=0,4: f*c + i*g
        hh = tanh_fast(c) * ov;                // other lanes: garbage, unused

        if (gl == 0) {
            hP[(t + 1) & 1][rowL >> 4][rowL & 15] = hh;
            hob[(size_t)t * H_ + rowL] = hh;
        }
        tv = table0[idxn * TPITCH + toff];     // prefetch next addend (L2)
        __syncthreads();
    }
    if (gl == 0) { h0st[b * H_ + rowL] = hh; c0st[b * H_ + rowL] = c; }
}

// ---------------- P2: xg1 = h0 @ wx1 + b1 ----------------
__global__ __launch_bounds__(G4, 2)
void gemm_xg1(const float* __restrict__ h0buf,
              const float* __restrict__ wx1,
              const float* __restrict__ b1,
              float* __restrict__ xg1)
{
    const int j  = threadIdx.x;
    const size_t m0 = (size_t)blockIdx.x * 64;
    const int c  = j & 127;          // cols c, c+128, c+256, c+384
    const int rg = j >> 7;           // rows rg*16 .. rg*16+15

    __shared__ __align__(16) float aT[64 * 132];   // row-major [r][k], pad 132

#pragma unroll
    for (int i = 0; i < 4; ++i) {
        const int e  = i * G4 + j;       // float4 index 0..2047
        const int r  = e >> 5;           // 32 float4 per row
        const int k4 = e & 31;
        const float4 v = *reinterpret_cast<const float4*>(&h0buf[(m0 + r) * H_ + k4 * 4]);
        *reinterpret_cast<float4*>(&aT[r * 132 + k4 * 4]) = v;
    }
    __syncthreads();

    float acc[4][16];
#pragma unroll
    for (int cc = 0; cc < 4; ++cc)
#pragma unroll
        for (int rr = 0; rr < 16; ++rr) acc[cc][rr] = 0.f;

    for (int k4 = 0; k4 < 32; ++k4) {
        float bv[4][4];   // [kk][cc]
#pragma unroll
        for (int kk = 0; kk < 4; ++kk)
#pragma unroll
            for (int cc = 0; cc < 4; ++cc)
                bv[kk][cc] = wx1[(size_t)(k4 * 4 + kk) * G4 + cc * 128 + c];
#pragma unroll
        for (int rr = 0; rr < 16; ++rr) {
            const float4 av = *reinterpret_cast<const float4*>(&aT[(rg * 16 + rr) * 132 + k4 * 4]);
#pragma unroll
            for (int cc = 0; cc < 4; ++cc) {
                acc[cc][rr] = fmaf(av.x, bv[0][cc], acc[cc][rr]);
                acc[cc][rr] = fmaf(av.y, bv[1][cc], acc[cc][rr]);
                acc[cc][rr] = fmaf(av.z, bv[2][cc], acc[cc][rr]);
                acc[cc][rr] = fmaf(av.w, bv[3][cc], acc[cc][rr]);
            }
        }
    }

    float b1v[4];
#pragma unroll
    for (int cc = 0; cc < 4; ++cc) b1v[cc] = b1[cc * 128 + c];
#pragma unroll
    for (int rr = 0; rr < 16; ++rr) {
        const size_t row = m0 + rg * 16 + rr;
#pragma unroll
        for (int cc = 0; cc < 4; ++cc)
            xg1[row * G4 + cc * 128 + c] = acc[cc][rr] + b1v[cc];
    }
}

// ---------------- P3: layer-1 recurrence (oct x k-eighth) ----------------
__global__ __launch_bounds__(512, 2)
void lstm_l1_chunk(const float* __restrict__ xg1,
                   const float* __restrict__ wh1,
                   float* __restrict__ h1st, float* __restrict__ c1st,
                   float* __restrict__ h1buf,
                   int TC)
{
    const int j = threadIdx.x;
    const int o = j >> 3;
    const int s = j & 7;
    const int b = blockIdx.x;
    const int gl = s & 3;
    const int rowL = 2 * o + (s >> 2);

    __shared__ __align__(16) float hP[2][8][36];

    const float* wmat = wh1;
    REPEAT16(DECLW)
    REPEAT16(LOADW)
    if (j < H_) hP[0][j >> 4][j & 15] = h1st[b * H_ + j];
    float c = c1st[b * H_ + rowL];
    float hh = 0.f;
    __syncthreads();

    const float* xgb = xg1 + (size_t)b * TC * G4;
    float* hob = h1buf + (size_t)b * TC * H_;
    const float A = (gl == 2) ? 2.f : 1.f;
    const int xcol = gl * H_ + rowL;
    const bool s0 = (s & 1), s1 = (s & 2), s2 = (s & 4);

    float xv = xgb[xcol];
    for (int t = 0; t < TC; ++t) {
        const float xvn = (t + 1 < TC) ? xgb[(size_t)(t + 1) * G4 + xcol] : 0.f;

        const float4* hb4 = reinterpret_cast<const float4*>(&hP[t & 1][s][0]);
        const float4 u0 = hb4[0], u1 = hb4[1], u2 = hb4[2], u3 = hb4[3];

        float a0 = 0.f, a1 = 0.f, a2 = 0.f, a3 = 0.f,
              a4 = 0.f, a5 = 0.f, a6 = 0.f, a7 = 0.f;
        FMAK(0,  u0.x) FMAK(1,  u0.y) FMAK(2,  u0.z) FMAK(3,  u0.w)
        FMAK(4,  u1.x) FMAK(5,  u1.y) FMAK(6,  u1.z) FMAK(7,  u1.w)
        FMAK(8,  u2.x) FMAK(9,  u2.y) FMAK(10, u2.z) FMAK(11, u2.w)
        FMAK(12, u3.x) FMAK(13, u3.y) FMAK(14, u3.z) FMAK(15, u3.w)

        a0 = sum8(a0); a1 = sum8(a1); a2 = sum8(a2); a3 = sum8(a3);
        a4 = sum8(a4); a5 = sum8(a5); a6 = sum8(a6); a7 = sum8(a7);

        const float t0_ = s0 ? a1 : a0;
        const float t1_ = s0 ? a3 : a2;
        const float t2_ = s0 ? a5 : a4;
        const float t3_ = s0 ? a7 : a6;
        const float u0_ = s1 ? t1_ : t0_;
        const float u1_ = s1 ? t3_ : t2_;
        const float val = (s2 ? u1_ : u0_) + xv;   // xg1 already includes b1

        const float tz  = __expf(A * val);
        const float act = fmaf(-A, __builtin_amdgcn_rcpf(tz + 1.f), 1.f);

        const float iv = dppmov<0x39>(act);
        const float gv = dppmov<0x4E>(act);
        const float ov = dppmov<0x93>(act);
        c  = fmaf(act, c, iv * gv);
        hh = tanh_fast(c) * ov;

        if (gl == 0) {
            hP[(t + 1) & 1][rowL >> 4][rowL & 15] = hh;
            hob[(size_t)t * H_ + rowL] = hh;
        }
        xv = xvn;
        __syncthreads();
    }
    if (gl == 0) { h1st[b * H_ + rowL] = hh; c1st[b * H_ + rowL] = c; }
}

// ---------------- P4: y = h1 @ why + by ----------------
__global__ __launch_bounds__(256)
void proj_y(const float* __restrict__ h1buf,
            const float* __restrict__ why,
            const float* __restrict__ by,
            float* __restrict__ out,
            int t0, int TC)
{
    const int tid = threadIdx.x;
    const int b   = blockIdx.x;

    __shared__ __align__(16) float whyS[V_][H_];   // [v][k], broadcast-read
    __shared__ float byS[V_];
    __shared__ float yS[256][29];                  // pad 29: conflict-free stage

    for (int e = tid; e < V_ * H_; e += 256) {
        const int v = e / H_, k = e - v * H_;
        whyS[v][k] = why[k * V_ + v];
    }
    if (tid < V_) byS[tid] = by[tid];
    __syncthreads();

    const float* hb  = h1buf + (size_t)b * TC * H_;
    float* outb      = out + ((size_t)b * T_ + t0) * V_;

    for (int tt0 = 0; tt0 < TC; tt0 += 256) {
        const int tt = tt0 + tid;
        if (tt < TC) {
            float acc[V_];
#pragma unroll
            for (int v = 0; v < V_; ++v) acc[v] = byS[v];
            const float4* hr = reinterpret_cast<const float4*>(hb + (size_t)tt * H_);
#pragma unroll 4
            for (int k4 = 0; k4 < 32; ++k4) {
                const float4 hv = hr[k4];
#pragma unroll
                for (int v = 0; v < V_; ++v) {
                    const float4 wv = *reinterpret_cast<const float4*>(&whyS[v][k4 * 4]);
                    acc[v] = fmaf(hv.x, wv.x,
                             fmaf(hv.y, wv.y,
                             fmaf(hv.z, wv.z,
                             fmaf(hv.w, wv.w, acc[v]))));
                }
            }
#pragma unroll
            for (int v = 0; v < V_; ++v) yS[tid][v] = acc[v];
        }
        __syncthreads();
        const int nrow = (TC - tt0 < 256) ? (TC - tt0) : 256;
        const int n = nrow * V_;
        float* od = outb + (size_t)tt0 * V_;
        for (int i = tid; i < n; i += 256) {
            const int r = i / V_, v = i - r * V_;
            od[i] = yS[r][v];
        }
        __syncthreads();
    }
}

// ---------------- fallback: streaming kernel (uses [v][4][132] table) ----------------
__global__ __launch_bounds__(G4, 1)
void lstm_persist(const int* __restrict__ x,
                  const float* __restrict__ table0,
                  const float* __restrict__ wh0,
                  const float* __restrict__ wx1,
                  const float* __restrict__ wh1,
                  const float* __restrict__ b1,
                  const float* __restrict__ why,
                  const float* __restrict__ by,
                  float* __restrict__ out)
{
    const int j  = threadIdx.x;
    const int bb = blockIdx.x * 2;

    __shared__ float h0s[2][H_], c0s[2][H_], h1s[2][H_], c1s[2][H_];
    __shared__ float hcat[2][2 * H_];
    __shared__ float g0s[2][G4], g1s[2][G4];
    __shared__ float whyS[H_ * V_];
    __shared__ float b1S[G4];
    __shared__ float byS[V_];
    __shared__ float pb[2][V_][8];

    for (int i = j; i < H_ * V_; i += G4) whyS[i] = why[i];
    b1S[j] = b1[j];
    if (j < V_) byS[j] = by[j];
    if (j < H_) {
        h0s[0][j] = 0.f; h0s[1][j] = 0.f; c0s[0][j] = 0.f; c0s[1][j] = 0.f;
        h1s[0][j] = 0.f; h1s[1][j] = 0.f; c1s[0][j] = 0.f; c1s[1][j] = 0.f;
    }
    __syncthreads();

    const int* xA = x + (size_t)(bb + 0) * T_;
    const int* xB = x + (size_t)(bb + 1) * T_;
    float* outA = out + (size_t)(bb + 0) * T_ * V_;
    float* outB = out + (size_t)(bb + 1) * T_ * V_;

    const int tix = (j >> 7) * 132 + (j & (H_ - 1));

    for (int t = 0; t < T_; ++t) {
        const int ia = xA[t];
        const int ib = xB[t];
        float aA = table0[ia * TPITCH + tix];
        float aB = table0[ib * TPITCH + tix];
#pragma unroll 8
        for (int k = 0; k < H_; ++k) {
            const float w = wh0[k * G4 + j];
            aA += h0s[0][k] * w;
            aB += h0s[1][k] * w;
        }
        g0s[0][j] = aA; g0s[1][j] = aB;
        __syncthreads();

        if (j < 2 * H_) {
            const int gi = j >> 7, r = j & (H_ - 1);
            const float f  = 1.f / (1.f + expf(-g0s[gi][r]));
            const float i_ = 1.f / (1.f + expf(-g0s[gi][H_ + r]));
            const float g  = tanhf(g0s[gi][2 * H_ + r]);
            const float o  = 1.f / (1.f + expf(-g0s[gi][3 * H_ + r]));
            const float c  = f * c0s[gi][r] + i_ * g;
            c0s[gi][r] = c;
            const float h = tanhf(c) * o;
            h0s[gi][r] = h;
            hcat[gi][r] = h;
            hcat[gi][H_ + r] = h1s[gi][r];
        }
        __syncthreads();

        float bA = b1S[j];
        float bB = bA;
#pragma unroll 8
        for (int k = 0; k < H_; ++k) {
            const float w = wx1[k * G4 + j];
            bA += hcat[0][k] * w;
            bB += hcat[1][k] * w;
        }
#pragma unroll 8
        for (int k = 0; k < H_; ++k) {
            const float w = wh1[k * G4 + j];
            bA += hcat[0][H_ + k] * w;
            bB += hcat[1][H_ + k] * w;
        }
        g1s[0][j] = bA; g1s[1][j] = bB;
        __syncthreads();

        if (j < 2 * H_) {
            const int gi = j >> 7, r = j & (H_ - 1);
            const float f  = 1.f / (1.f + expf(-g1s[gi][r]));
            const float i_ = 1.f / (1.f + expf(-g1s[gi][H_ + r]));
            const float g  = tanhf(g1s[gi][2 * H_ + r]);
            const float o  = 1.f / (1.f + expf(-g1s[gi][3 * H_ + r]));
            const float c  = f * c1s[gi][r] + i_ * g;
            c1s[gi][r] = c;
            h1s[gi][r] = tanhf(c) * o;
        }
        __syncthreads();

        if (j < 2 * V_ * 8) {
            int qq = j;
            const int gi = (qq >= V_ * 8) ? 1 : 0;
            qq -= gi * V_ * 8;
            const int v = qq >> 3, kk = qq & 7;
            float pv = 0.f;
#pragma unroll
            for (int k = kk * 16; k < kk * 16 + 16; ++k)
                pv += h1s[gi][k] * whyS[k * V_ + v];
            pb[gi][v][kk] = pv;
        }
        __syncthreads();

        if (j < 2 * V_) {
            const int gi = (j >= V_) ? 1 : 0;
            const int v  = j - gi * V_;
            float sA = byS[v];
#pragma unroll
            for (int qq = 0; qq < 8; ++qq) sA += pb[gi][v][qq];
            (gi ? outB : outA)[t * V_ + v] = sA;
        }
        __syncthreads();
    }
}

// ---------------- host ----------------
extern "C" void kernel_launch(void* const* d_in, const int* in_sizes, int n_in,
                              void* d_out, int out_size, void* d_ws, size_t ws_size,
                              hipStream_t stream)
{
    const int*   x   = (const int*)  d_in[0];
    const float* emb = (const float*)d_in[1];
    const float* wx0 = (const float*)d_in[2];
    const float* wh0 = (const float*)d_in[3];
    const float* b0  = (const float*)d_in[4];
    const float* wx1 = (const float*)d_in[5];
    const float* wh1 = (const float*)d_in[6];
    const float* b1  = (const float*)d_in[7];
    const float* why = (const float*)d_in[8];
    const float* by  = (const float*)d_in[9];
    float* out = (float*)d_out;
    float* wsf = (float*)d_ws;

    const size_t tabF   = (size_t)V_ * TPITCH;   // 14256 floats
    const size_t stateF = (size_t)4 * B_ * H_;   // 131072 floats

    int TC = 0;
    for (int tc = T_; tc >= 32; tc >>= 1) {
        // per-chunk buffers: h0buf (H) + xg1buf (G4) + h1buf (H) per (b,t)
        const size_t need = (tabF + stateF + (size_t)B_ * tc * (H_ + G4 + H_)) * 4;
        if (need <= ws_size) { TC = tc; break; }
    }

    float* table0 = wsf;
    build_table0<<<dim3(V_), dim3(G4), 0, stream>>>(emb, wx0, b0, table0);

    if (TC == 0) {
        lstm_persist<<<dim3(B_ / 2), dim3(G4), 0, stream>>>(
            x, table0, wh0, wx1, wh1, b1, why, by, out);
        return;
    }

    float* h0st   = wsf + tabF;
    float* c0st   = h0st + (size_t)B_ * H_;
    float* h1st   = c0st + (size_t)B_ * H_;
    float* c1st   = h1st + (size_t)B_ * H_;
    float* h0buf  = c1st + (size_t)B_ * H_;
    float* xg1buf = h0buf + (size_t)B_ * TC * H_;
    float* h1buf  = xg1buf + (size_t)B_ * TC * G4;

    (void)hipMemsetAsync(h0st, 0, stateF * sizeof(float), stream);

    const int NC = T_ / TC;
    for (int c = 0; c < NC; ++c) {
        const int t0 = c * TC;
        lstm_l0_chunk<<<dim3(B_), dim3(512), 0, stream>>>(
            x, table0, wh0, h0st, c0st, h0buf, t0, TC);
        gemm_xg1<<<dim3(4 * TC), dim3(G4), 0, stream>>>(
            h0buf, wx1, b1, xg1buf);
        lstm_l1_chunk<<<dim3(B_), dim3(512), 0, stream>>>(
            xg1buf, wh1, h1st, c1st, h1buf, TC);
        proj_y<<<dim3(B_), dim3(256), 0, stream>>>(
            h1buf, why, by, out, t0, TC);
    }
}

// Round 16
// 1871.453 us; speedup vs baseline: 1.1386x; 1.0686x over previous
//
#include <hip/hip_runtime.h>

// MultiLayerLSTM: B=256, T=1024, V=27, E=64, H=128 (4H=512)
// Round 16: revert to the verified-best round-11 configuration (1856 us).
//   Design-space sweep r8-r15 bracketed the recurrence optimum:
//   512 thr, thread=(row p, k-quarter e), 128 weights/thread (register-
//   resident; one matrix = half the register file -> 1 block/CU forced),
//   2-stage qsum DPP reduce, unified activation via __expf + rcp, DPP
//   quad gathers, 1 barrier/step, [2][4][36] conflict-free h ping-pong.
//   gemm_xg1 measures ~83% of fp32 vector peak (compute-bound).
// Phases: P0 table, P1 l0, P2 GEMM xg1=h0@wx1+b1, P3 l1, P4 proj_y.

#define B_  256
#define T_  1024
#define V_  27
#define E_  64
#define H_  128
#define G4  512     // 4*H
#define TPITCH 528  // 4*132 padded table pitch per vocab entry

typedef float v2f __attribute__((ext_vector_type(2)));

__device__ __forceinline__ v2f mkv2(float a, float b) { v2f r; r.x = a; r.y = b; return r; }

template <int CTRL>
__device__ __forceinline__ float dppmov(float v) {
    return __int_as_float(__builtin_amdgcn_update_dpp(
               0, __float_as_int(v), CTRL, 0xF, 0xF, true));
}
__device__ __forceinline__ float qsum(float v) {
    v += dppmov<0xB1>(v);   // quad_perm [1,0,3,2]
    v += dppmov<0x4E>(v);   // quad_perm [2,3,0,1]
    return v;
}
__device__ __forceinline__ float tanh_fast(float y) {
    const float t = __expf(2.f * y);             // inf-safe: tanh(+big)=1
    return fmaf(-2.f, __builtin_amdgcn_rcpf(t + 1.f), 1.f);
}

#define REPEAT16(M) M(0) M(1) M(2) M(3) M(4) M(5) M(6) M(7) \
                    M(8) M(9) M(10) M(11) M(12) M(13) M(14) M(15)

#define DECLW(K) v2f wf##K, wi##K, wg##K, wo##K;
#define LOADW(K) { const float* r0 = wmat + (size_t)(kb + 2*(K)) * G4; \
                   wf##K = mkv2(r0[p],          r0[G4 + p]); \
                   wi##K = mkv2(r0[H_ + p],     r0[G4 + H_ + p]); \
                   wg##K = mkv2(r0[2*H_ + p],   r0[G4 + 2*H_ + p]); \
                   wo##K = mkv2(r0[3*H_ + p],   r0[G4 + 3*H_ + p]); }
// empty asm: forces the 4 v2f weight values into arch VGPRs at this point
#define PINW(K) asm("" : "+v"(wf##K), "+v"(wi##K), "+v"(wg##K), "+v"(wo##K));
#define FMAP(K, HA, HB) { const v2f h2 = mkv2(HA, HB); \
    sf2 = __builtin_elementwise_fma(h2, wf##K, sf2); \
    si2 = __builtin_elementwise_fma(h2, wi##K, si2); \
    sg2 = __builtin_elementwise_fma(h2, wg##K, sg2); \
    so2 = __builtin_elementwise_fma(h2, wo##K, so2); }

#define FMABODY \
    v2f sf2 = mkv2(0.f, 0.f), si2 = sf2, sg2 = sf2, so2 = sf2; \
    FMAP(0,  v0.x, v0.y) FMAP(1,  v0.z, v0.w) \
    FMAP(2,  v1.x, v1.y) FMAP(3,  v1.z, v1.w) \
    FMAP(4,  v2.x, v2.y) FMAP(5,  v2.z, v2.w) \
    FMAP(6,  v3.x, v3.y) FMAP(7,  v3.z, v3.w) \
    FMAP(8,  v4.x, v4.y) FMAP(9,  v4.z, v4.w) \
    FMAP(10, v5.x, v5.y) FMAP(11, v5.z, v5.w) \
    FMAP(12, v6.x, v6.y) FMAP(13, v6.z, v6.w) \
    FMAP(14, v7.x, v7.y) FMAP(15, v7.z, v7.w)

// ---------------- P0: token table, layout [v][4][132] ----------------
__global__ __launch_bounds__(G4)
void build_table0(const float* __restrict__ emb,
                  const float* __restrict__ wx0,
                  const float* __restrict__ b0,
                  float* __restrict__ table0)
{
    const int v = blockIdx.x;        // 0..26
    const int j = threadIdx.x;       // col 0..511
    __shared__ float e[E_];
    if (j < E_) e[j] = emb[v * E_ + j];
    __syncthreads();
    float s = b0[j];
#pragma unroll 8
    for (int k = 0; k < E_; ++k) s = fmaf(e[k], wx0[k * G4 + j], s);
    const int r = j & (H_ - 1), gate = j >> 7;
    table0[v * TPITCH + gate * 132 + r] = s;
}

// ---------------- P1: layer-0 recurrence (row x k-quarter) ----------------
__global__ __launch_bounds__(512, 2)
void lstm_l0_chunk(const int* __restrict__ x,
                   const float* __restrict__ table0,
                   const float* __restrict__ wh0,
                   float* __restrict__ h0st, float* __restrict__ c0st,
                   float* __restrict__ h0buf,
                   int t0, int TC)
{
    const int j = threadIdx.x;        // 0..511
    const int p = j >> 2;             // row 0..127
    const int e = j & 3;              // k-quarter
    const int b = blockIdx.x;
    const int kb = 32 * e;

    __shared__ __align__(16) float hP[2][4][36];     // pad 36: conflict-free

    const float* wmat = wh0;
    REPEAT16(DECLW)
    REPEAT16(LOADW)
    if (j < H_) hP[0][j >> 5][j & 31] = h0st[b * H_ + j];
    float c = c0st[b * H_ + p];
    float hh = 0.f;
    __syncthreads();

    const int* xb = x + (size_t)b * T_ + t0;
    float* hob = h0buf + (size_t)b * TC * H_;
    const float A = (e == 2) ? 2.f : 1.f;   // tanh for g-gate, sigmoid else
    const int toff = (e & 3) * 132 + p;

    float tv = table0[xb[0] * TPITCH + toff];
    for (int t = 0; t < TC; ++t) {
        REPEAT16(PINW)
        const int idxn = (t + 1 < TC) ? xb[t + 1] : 0;

        const float4* hb4 = reinterpret_cast<const float4*>(&hP[t & 1][e][0]);
        const float4 v0 = hb4[0], v1 = hb4[1], v2 = hb4[2], v3 = hb4[3],
                     v4 = hb4[4], v5 = hb4[5], v6 = hb4[6], v7 = hb4[7];
        FMABODY
        const float sf = qsum(sf2.x + sf2.y);
        const float si = qsum(si2.x + si2.y);
        const float sg = qsum(sg2.x + sg2.y);
        const float so = qsum(so2.x + so2.y);

        float val = (e == 0) ? sf : (e == 1) ? si : (e == 2) ? sg : so;
        val += tv;
        const float tz  = __expf(A * val);
        const float act = fmaf(-A, __builtin_amdgcn_rcpf(tz + 1.f), 1.f);

        const float iv = dppmov<0x39>(act);   // lane0 <- lane1 (i)
        const float gv = dppmov<0x4E>(act);   // lane0 <- lane2 (g)
        const float ov = dppmov<0x93>(act);   // lane0 <- lane3 (o)
        c  = fmaf(act, c, iv * gv);           // lane0: f*c + i*g
        hh = tanh_fast(c) * ov;               // lanes 1-3: garbage, unused

        if (e == 0) {
            hP[(t + 1) & 1][p >> 5][p & 31] = hh;
            hob[(size_t)t * H_ + p] = hh;
        }
        tv = table0[idxn * TPITCH + toff];
        __syncthreads();
    }
    if (e == 0) { h0st[b * H_ + p] = hh; c0st[b * H_ + p] = c; }
}

// ---------------- P2: xg1 = h0 @ wx1 + b1 ----------------
__global__ __launch_bounds__(G4, 2)
void gemm_xg1(const float* __restrict__ h0buf,
              const float* __restrict__ wx1,
              const float* __restrict__ b1,
              float* __restrict__ xg1)
{
    const int j  = threadIdx.x;
    const size_t m0 = (size_t)blockIdx.x * 64;
    const int c  = j & 127;          // cols c, c+128, c+256, c+384
    const int rg = j >> 7;           // rows rg*16 .. rg*16+15

    __shared__ __align__(16) float aT[64 * 132];   // row-major [r][k], pad 132

#pragma unroll
    for (int i = 0; i < 4; ++i) {
        const int e  = i * G4 + j;       // float4 index 0..2047
        const int r  = e >> 5;           // 32 float4 per row
        const int k4 = e & 31;
        const float4 v = *reinterpret_cast<const float4*>(&h0buf[(m0 + r) * H_ + k4 * 4]);
        *reinterpret_cast<float4*>(&aT[r * 132 + k4 * 4]) = v;
    }
    __syncthreads();

    float acc[4][16];
#pragma unroll
    for (int cc = 0; cc < 4; ++cc)
#pragma unroll
        for (int rr = 0; rr < 16; ++rr) acc[cc][rr] = 0.f;

    for (int k4 = 0; k4 < 32; ++k4) {
        float bv[4][4];   // [kk][cc]
#pragma unroll
        for (int kk = 0; kk < 4; ++kk)
#pragma unroll
            for (int cc = 0; cc < 4; ++cc)
                bv[kk][cc] = wx1[(size_t)(k4 * 4 + kk) * G4 + cc * 128 + c];
#pragma unroll
        for (int rr = 0; rr < 16; ++rr) {
            const float4 av = *reinterpret_cast<const float4*>(&aT[(rg * 16 + rr) * 132 + k4 * 4]);
#pragma unroll
            for (int cc = 0; cc < 4; ++cc) {
                acc[cc][rr] = fmaf(av.x, bv[0][cc], acc[cc][rr]);
                acc[cc][rr] = fmaf(av.y, bv[1][cc], acc[cc][rr]);
                acc[cc][rr] = fmaf(av.z, bv[2][cc], acc[cc][rr]);
                acc[cc][rr] = fmaf(av.w, bv[3][cc], acc[cc][rr]);
            }
        }
    }

    float b1v[4];
#pragma unroll
    for (int cc = 0; cc < 4; ++cc) b1v[cc] = b1[cc * 128 + c];
#pragma unroll
    for (int rr = 0; rr < 16; ++rr) {
        const size_t row = m0 + rg * 16 + rr;
#pragma unroll
        for (int cc = 0; cc < 4; ++cc)
            xg1[row * G4 + cc * 128 + c] = acc[cc][rr] + b1v[cc];
    }
}

// ---------------- P3: layer-1 recurrence (row x k-quarter) ----------------
__global__ __launch_bounds__(512, 2)
void lstm_l1_chunk(const float* __restrict__ xg1,
                   const float* __restrict__ wh1,
                   float* __restrict__ h1st, float* __restrict__ c1st,
                   float* __restrict__ h1buf,
                   int TC)
{
    const int j = threadIdx.x;
    const int p = j >> 2;
    const int e = j & 3;
    const int b = blockIdx.x;
    const int kb = 32 * e;

    __shared__ __align__(16) float hP[2][4][36];

    const float* wmat = wh1;
    REPEAT16(DECLW)
    REPEAT16(LOADW)
    if (j < H_) hP[0][j >> 5][j & 31] = h1st[b * H_ + j];
    float c = c1st[b * H_ + p];
    float hh = 0.f;
    __syncthreads();

    const float* xgb = xg1 + (size_t)b * TC * G4;
    float* hob = h1buf + (size_t)b * TC * H_;
    const float A = (e == 2) ? 2.f : 1.f;
    const int xcol = e * H_ + p;              // gate-e column for row p

    float xv = xgb[xcol];
    for (int t = 0; t < TC; ++t) {
        REPEAT16(PINW)
        const float xvn = (t + 1 < TC) ? xgb[(size_t)(t + 1) * G4 + xcol] : 0.f;

        const float4* hb4 = reinterpret_cast<const float4*>(&hP[t & 1][e][0]);
        const float4 v0 = hb4[0], v1 = hb4[1], v2 = hb4[2], v3 = hb4[3],
                     v4 = hb4[4], v5 = hb4[5], v6 = hb4[6], v7 = hb4[7];
        FMABODY
        const float sf = qsum(sf2.x + sf2.y);
        const float si = qsum(si2.x + si2.y);
        const float sg = qsum(sg2.x + sg2.y);
        const float so = qsum(so2.x + so2.y);

        float val = (e == 0) ? sf : (e == 1) ? si : (e == 2) ? sg : so;
        val += xv;                            // xg1 already includes b1
        const float tz  = __expf(A * val);
        const float act = fmaf(-A, __builtin_amdgcn_rcpf(tz + 1.f), 1.f);

        const float iv = dppmov<0x39>(act);
        const float gv = dppmov<0x4E>(act);
        const float ov = dppmov<0x93>(act);
        c  = fmaf(act, c, iv * gv);
        hh = tanh_fast(c) * ov;

        if (e == 0) {
            hP[(t + 1) & 1][p >> 5][p & 31] = hh;
            hob[(size_t)t * H_ + p] = hh;
        }
        xv = xvn;
        __syncthreads();
    }
    if (e == 0) { h1st[b * H_ + p] = hh; c1st[b * H_ + p] = c; }
}

// ---------------- P4: y = h1 @ why + by ----------------
__global__ __launch_bounds__(256)
void proj_y(const float* __restrict__ h1buf,
            const float* __restrict__ why,
            const float* __restrict__ by,
            float* __restrict__ out,
            int t0, int TC)
{
    const int tid = threadIdx.x;
    const int b   = blockIdx.x;

    __shared__ __align__(16) float whyS[V_][H_];   // [v][k], broadcast-read
    __shared__ float byS[V_];
    __shared__ float yS[256][29];                  // pad 29: conflict-free stage

    for (int e = tid; e < V_ * H_; e += 256) {
        const int v = e / H_, k = e - v * H_;
        whyS[v][k] = why[k * V_ + v];
    }
    if (tid < V_) byS[tid] = by[tid];
    __syncthreads();

    const float* hb  = h1buf + (size_t)b * TC * H_;
    float* outb      = out + ((size_t)b * T_ + t0) * V_;

    for (int tt0 = 0; tt0 < TC; tt0 += 256) {
        const int tt = tt0 + tid;
        if (tt < TC) {
            float acc[V_];
#pragma unroll
            for (int v = 0; v < V_; ++v) acc[v] = byS[v];
            const float4* hr = reinterpret_cast<const float4*>(hb + (size_t)tt * H_);
#pragma unroll 4
            for (int k4 = 0; k4 < 32; ++k4) {
                const float4 hv = hr[k4];
#pragma unroll
                for (int v = 0; v < V_; ++v) {
                    const float4 wv = *reinterpret_cast<const float4*>(&whyS[v][k4 * 4]);
                    acc[v] = fmaf(hv.x, wv.x,
                             fmaf(hv.y, wv.y,
                             fmaf(hv.z, wv.z,
                             fmaf(hv.w, wv.w, acc[v]))));
                }
            }
#pragma unroll
            for (int v = 0; v < V_; ++v) yS[tid][v] = acc[v];
        }
        __syncthreads();
        const int nrow = (TC - tt0 < 256) ? (TC - tt0) : 256;
        const int n = nrow * V_;
        float* od = outb + (size_t)tt0 * V_;
        for (int i = tid; i < n; i += 256) {
            const int r = i / V_, v = i - r * V_;
            od[i] = yS[r][v];
        }
        __syncthreads();
    }
}

// ---------------- fallback: streaming kernel (uses [v][4][132] table) ----------------
__global__ __launch_bounds__(G4, 1)
void lstm_persist(const int* __restrict__ x,
                  const float* __restrict__ table0,
                  const float* __restrict__ wh0,
                  const float* __restrict__ wx1,
                  const float* __restrict__ wh1,
                  const float* __restrict__ b1,
                  const float* __restrict__ why,
                  const float* __restrict__ by,
                  float* __restrict__ out)
{
    const int j  = threadIdx.x;
    const int bb = blockIdx.x * 2;

    __shared__ float h0s[2][H_], c0s[2][H_], h1s[2][H_], c1s[2][H_];
    __shared__ float hcat[2][2 * H_];
    __shared__ float g0s[2][G4], g1s[2][G4];
    __shared__ float whyS[H_ * V_];
    __shared__ float b1S[G4];
    __shared__ float byS[V_];
    __shared__ float pb[2][V_][8];

    for (int i = j; i < H_ * V_; i += G4) whyS[i] = why[i];
    b1S[j] = b1[j];
    if (j < V_) byS[j] = by[j];
    if (j < H_) {
        h0s[0][j] = 0.f; h0s[1][j] = 0.f; c0s[0][j] = 0.f; c0s[1][j] = 0.f;
        h1s[0][j] = 0.f; h1s[1][j] = 0.f; c1s[0][j] = 0.f; c1s[1][j] = 0.f;
    }
    __syncthreads();

    const int* xA = x + (size_t)(bb + 0) * T_;
    const int* xB = x + (size_t)(bb + 1) * T_;
    float* outA = out + (size_t)(bb + 0) * T_ * V_;
    float* outB = out + (size_t)(bb + 1) * T_ * V_;

    const int tix = (j >> 7) * 132 + (j & (H_ - 1));

    for (int t = 0; t < T_; ++t) {
        const int ia = xA[t];
        const int ib = xB[t];
        float aA = table0[ia * TPITCH + tix];
        float aB = table0[ib * TPITCH + tix];
#pragma unroll 8
        for (int k = 0; k < H_; ++k) {
            const float w = wh0[k * G4 + j];
            aA += h0s[0][k] * w;
            aB += h0s[1][k] * w;
        }
        g0s[0][j] = aA; g0s[1][j] = aB;
        __syncthreads();

        if (j < 2 * H_) {
            const int gi = j >> 7, r = j & (H_ - 1);
            const float f  = 1.f / (1.f + expf(-g0s[gi][r]));
            const float i_ = 1.f / (1.f + expf(-g0s[gi][H_ + r]));
            const float g  = tanhf(g0s[gi][2 * H_ + r]);
            const float o  = 1.f / (1.f + expf(-g0s[gi][3 * H_ + r]));
            const float c  = f * c0s[gi][r] + i_ * g;
            c0s[gi][r] = c;
            const float h = tanhf(c) * o;
            h0s[gi][r] = h;
            hcat[gi][r] = h;
            hcat[gi][H_ + r] = h1s[gi][r];
        }
        __syncthreads();

        float bA = b1S[j];
        float bB = bA;
#pragma unroll 8
        for (int k = 0; k < H_; ++k) {
            const float w = wx1[k * G4 + j];
            bA += hcat[0][k] * w;
            bB += hcat[1][k] * w;
        }
#pragma unroll 8
        for (int k = 0; k < H_; ++k) {
            const float w = wh1[k * G4 + j];
            bA += hcat[0][H_ + k] * w;
            bB += hcat[1][H_ + k] * w;
        }
        g1s[0][j] = bA; g1s[1][j] = bB;
        __syncthreads();

        if (j < 2 * H_) {
            const int gi = j >> 7, r = j & (H_ - 1);
            const float f  = 1.f / (1.f + expf(-g1s[gi][r]));
            const float i_ = 1.f / (1.f + expf(-g1s[gi][H_ + r]));
            const float g  = tanhf(g1s[gi][2 * H_ + r]);
            const float o  = 1.f / (1.f + expf(-g1s[gi][3 * H_ + r]));
            const float c  = f * c1s[gi][r] + i_ * g;
            c1s[gi][r] = c;
            h1s[gi][r] = tanhf(c) * o;
        }
        __syncthreads();

        if (j < 2 * V_ * 8) {
            int qq = j;
            const int gi = (qq >= V_ * 8) ? 1 : 0;
            qq -= gi * V_ * 8;
            const int v = qq >> 3, kk = qq & 7;
            float pv = 0.f;
#pragma unroll
            for (int k = kk * 16; k < kk * 16 + 16; ++k)
                pv += h1s[gi][k] * whyS[k * V_ + v];
            pb[gi][v][kk] = pv;
        }
        __syncthreads();

        if (j < 2 * V_) {
            const int gi = (j >= V_) ? 1 : 0;
            const int v  = j - gi * V_;
            float sA = byS[v];
#pragma unroll
            for (int qq = 0; qq < 8; ++qq) sA += pb[gi][v][qq];
            (gi ? outB : outA)[t * V_ + v] = sA;
        }
        __syncthreads();
    }
}

// ---------------- host ----------------
extern "C" void kernel_launch(void* const* d_in, const int* in_sizes, int n_in,
                              void* d_out, int out_size, void* d_ws, size_t ws_size,
                              hipStream_t stream)
{
    const int*   x   = (const int*)  d_in[0];
    const float* emb = (const float*)d_in[1];
    const float* wx0 = (const float*)d_in[2];
    const float* wh0 = (const float*)d_in[3];
    const float* b0  = (const float*)d_in[4];
    const float* wx1 = (const float*)d_in[5];
    const float* wh1 = (const float*)d_in[6];
    const float* b1  = (const float*)d_in[7];
    const float* why = (const float*)d_in[8];
    const float* by  = (const float*)d_in[9];
    float* out = (float*)d_out;
    float* wsf = (float*)d_ws;

    const size_t tabF   = (size_t)V_ * TPITCH;   // 14256 floats
    const size_t stateF = (size_t)4 * B_ * H_;   // 131072 floats

    int TC = 0;
    for (int tc = T_; tc >= 32; tc >>= 1) {
        // per-chunk buffers: h0buf (H) + xg1buf (G4) + h1buf (H) per (b,t)
        const size_t need = (tabF + stateF + (size_t)B_ * tc * (H_ + G4 + H_)) * 4;
        if (need <= ws_size) { TC = tc; break; }
    }

    float* table0 = wsf;
    build_table0<<<dim3(V_), dim3(G4), 0, stream>>>(emb, wx0, b0, table0);

    if (TC == 0) {
        lstm_persist<<<dim3(B_ / 2), dim3(G4), 0, stream>>>(
            x, table0, wh0, wx1, wh1, b1, why, by, out);
        return;
    }

    float* h0st   = wsf + tabF;
    float* c0st   = h0st + (size_t)B_ * H_;
    float* h1st   = c0st + (size_t)B_ * H_;
    float* c1st   = h1st + (size_t)B_ * H_;
    float* h0buf  = c1st + (size_t)B_ * H_;
    float* xg1buf = h0buf + (size_t)B_ * TC * H_;
    float* h1buf  = xg1buf + (size_t)B_ * TC * G4;

    (void)hipMemsetAsync(h0st, 0, stateF * sizeof(float), stream);

    const int NC = T_ / TC;
    for (int c = 0; c < NC; ++c) {
        const int t0 = c * TC;
        lstm_l0_chunk<<<dim3(B_), dim3(512), 0, stream>>>(
            x, table0, wh0, h0st, c0st, h0buf, t0, TC);
        gemm_xg1<<<dim3(4 * TC), dim3(G4), 0, stream>>>(
            h0buf, wx1, b1, xg1buf);
        lstm_l1_chunk<<<dim3(B_), dim3(512), 0, stream>>>(
            xg1buf, wh1, h1st, c1st, h1buf, TC);
        proj_y<<<dim3(B_), dim3(256), 0, stream>>>(
            h1buf, why, by, out, t0, TC);
    }
}